// Round 1
// baseline (822.381 us; speedup 1.0000x reference)
//
#include <hip/hip_runtime.h>
#include <hip/hip_bf16.h>

#define B_ 64
#define S_ 4096
#define H_ 512
#define E_ 512
#define NEG_INF_ -1e10f

typedef __attribute__((ext_vector_type(8))) short short8;
typedef __attribute__((ext_vector_type(16))) float f32x16;

static __device__ __forceinline__ unsigned short f2bf(float f) {
    union { float f; unsigned u; } v; v.f = f;
    unsigned x = v.u;
    x += 0x7FFFu + ((x >> 16) & 1u);   // round-to-nearest-even
    return (unsigned short)(x >> 16);
}

// ---------------- prep: Wkt[h][e] = bf16(Wk[e][h]) ----------------
__global__ void prep_wkt(const float* __restrict__ wk, unsigned short* __restrict__ wkt) {
    int idx = blockIdx.x * 256 + threadIdx.x;      // 0..262143
    int h = idx >> 9, e = idx & 511;
    wkt[idx] = f2bf(wk[e * H_ + h]);
}

// ---------------- prep: qb[b][h] = hidden[b]@Wq[:,h] + bq[h] + bk[h] ----------------
__global__ void prep_qb(const float* __restrict__ hidden, const float* __restrict__ wq,
                        const float* __restrict__ bq, const float* __restrict__ bk,
                        float* __restrict__ qb) {
    __shared__ float hid[H_];
    int b = blockIdx.x, t = threadIdx.x;           // 256 threads
    hid[t]       = hidden[b * H_ + t];
    hid[t + 256] = hidden[b * H_ + t + 256];
    __syncthreads();
    for (int hh = t; hh < H_; hh += 256) {
        float s = 0.f;
        for (int e = 0; e < H_; ++e) s += hid[e] * wq[e * H_ + hh];
        qb[b * H_ + hh] = s + bq[hh] + bk[hh];
    }
}

// ---------------- main: scores[b][s] = Wv . tanh(qb[b] + enc[b,s,:]@Wk) + bv ----------------
// block: 256 threads (4 waves), Mtile=128 s-rows, N=512 in 4 n-tiles of 128, K=512 in 8 chunks of 64
// LDS: As [128][512] bf16 swizzled (131072 B) + Bt [128][64] bf16 swizzled (16384 B) = 147456 B
__global__ __launch_bounds__(256, 1) void scores_kernel(
    const float* __restrict__ enc, const unsigned short* __restrict__ wkt,
    const float* __restrict__ qb, const float* __restrict__ wv,
    const float* __restrict__ bvp, float* __restrict__ scores)
{
    extern __shared__ char lds[];
    char* As = lds;                 // byte(row,k) = row*1024 + ((2k) ^ ((row&15)<<4))
    char* Bt = lds + 131072;        // byte(row,k) = row*128  + ((2k) ^ ((row&7)<<4))

    const int b    = blockIdx.y;
    const int s0   = blockIdx.x * 128;
    const int tid  = threadIdx.x;
    const int lane = tid & 63;
    const int wave = tid >> 6;       // 0..3
    const int l31  = lane & 31;
    const int g    = lane >> 5;      // 0,1

    const float* encb = enc + (size_t)b * S_ * E_ + (size_t)s0 * E_;
    const float bv0 = bvp[0];

    float4 asreg[8];
    uint4  btcur[4], btnxt[4];

    // prologue: prefetch As piece 0 (k-cols 0..63) and Bt tile 0
#pragma unroll
    for (int i = 0; i < 8; ++i) {
        int id = i * 256 + tid; int row = id >> 4; int c4 = id & 15;
        asreg[i] = *(const float4*)(encb + row * 512 + c4 * 4);
    }
#pragma unroll
    for (int i = 0; i < 4; ++i) {
        int id = i * 256 + tid; int row = id >> 3; int c4 = id & 7;
        btcur[i] = *(const uint4*)(wkt + row * 512 + c4 * 8);
    }

    float p[16];
#pragma unroll
    for (int r = 0; r < 16; ++r) p[r] = 0.f;

    for (int nt = 0; nt < 4; ++nt) {
        f32x16 acc[4];
#pragma unroll
        for (int nf = 0; nf < 4; ++nf)
#pragma unroll
            for (int r = 0; r < 16; ++r) acc[nf][r] = 0.f;

        for (int kc = 0; kc < 8; ++kc) {
            int t_lin = nt * 8 + kc;
            __syncthreads();
            // write Bt chunk (nt, kc)
#pragma unroll
            for (int i = 0; i < 4; ++i) {
                int id = i * 256 + tid; int row = id >> 3; int c4 = id & 7;
                *(uint4*)(Bt + row * 128 + ((c4 * 16) ^ ((row & 7) << 4))) = btcur[i];
            }
            // write As piece kc (only on the first n-tile pass)
            if (nt == 0) {
#pragma unroll
                for (int i = 0; i < 8; ++i) {
                    int id = i * 256 + tid; int row = id >> 4; int c4 = id & 15;
                    float4 v = asreg[i];
                    ushort4 pk = { f2bf(v.x), f2bf(v.y), f2bf(v.z), f2bf(v.w) };
                    *(ushort4*)(As + row * 1024 + ((kc * 128 + c4 * 8) ^ ((row & 15) << 4))) = pk;
                }
            }
            // prefetch next Bt tile
            if (t_lin < 31) {
                int nt2 = (t_lin + 1) >> 3, kc2 = (t_lin + 1) & 7;
#pragma unroll
                for (int i = 0; i < 4; ++i) {
                    int id = i * 256 + tid; int row = id >> 3; int c4 = id & 7;
                    btnxt[i] = *(const uint4*)(wkt + (nt2 * 128 + row) * 512 + kc2 * 64 + c4 * 8);
                }
            }
            // prefetch next As piece
            if (nt == 0 && kc < 7) {
#pragma unroll
                for (int i = 0; i < 8; ++i) {
                    int id = i * 256 + tid; int row = id >> 4; int c4 = id & 15;
                    asreg[i] = *(const float4*)(encb + row * 512 + (kc + 1) * 64 + c4 * 4);
                }
            }
            __syncthreads();
            // MFMA: 4 k-steps x 4 n-frags
#pragma unroll
            for (int ks = 0; ks < 4; ++ks) {
                int arow = wave * 32 + l31;
                short8 af = *(const short8*)(As + arow * 1024 +
                             ((kc * 128 + ks * 32 + g * 16) ^ ((arow & 15) << 4)));
#pragma unroll
                for (int nf = 0; nf < 4; ++nf) {
                    int brow = nf * 32 + l31;
                    short8 bfr = *(const short8*)(Bt + brow * 128 +
                                  ((ks * 32 + g * 16) ^ ((brow & 7) << 4)));
                    acc[nf] = __builtin_amdgcn_mfma_f32_32x32x16_bf16(af, bfr, acc[nf], 0, 0, 0);
                }
            }
#pragma unroll
            for (int i = 0; i < 4; ++i) btcur[i] = btnxt[i];
        }
        // epilogue: p[r] += tanh(qb + k) * Wv over this n-tile's 4 cols per lane
#pragma unroll
        for (int nf = 0; nf < 4; ++nf) {
            int col = nt * 128 + nf * 32 + l31;
            float qv  = qb[b * H_ + col];
            float wvv = wv[col];
#pragma unroll
            for (int r = 0; r < 16; ++r) {
                float x = qv + acc[nf][r];
                float e = __expf(2.f * x);
                float th = 1.f - 2.f / (e + 1.f);   // inf-safe: x>>0 -> 1, x<<0 -> -1
                p[r] += th * wvv;
            }
        }
    }
    // butterfly reduce over the 32 lanes of each half (rows identical within a half)
#pragma unroll
    for (int r = 0; r < 16; ++r) {
        float v = p[r];
        v += __shfl_xor(v, 1);
        v += __shfl_xor(v, 2);
        v += __shfl_xor(v, 4);
        v += __shfl_xor(v, 8);
        v += __shfl_xor(v, 16);
        p[r] = v + bv0;
    }
    if (l31 == 0) {
        float* srow = scores + (size_t)b * S_ + s0 + wave * 32 + g * 4;
#pragma unroll
        for (int r = 0; r < 16; ++r)
            srow[(r & 3) + 8 * (r >> 2)] = p[r];
    }
}

// ---------------- masked softmax over S per batch row ----------------
__global__ void softmax_kernel(const float* __restrict__ scores, const int* __restrict__ mask,
                               float* __restrict__ attn) {
    __shared__ float red[8];
    int b = blockIdx.x, tid = threadIdx.x;         // 512 threads, 8 waves
    int wid = tid >> 6, lane = tid & 63;
    float vals[8];
    float mx = -3.4e38f;
#pragma unroll
    for (int i = 0; i < 8; ++i) {
        int s = i * 512 + tid;
        float sc = scores[(size_t)b * S_ + s];
        sc = mask[(size_t)b * S_ + s] ? sc : NEG_INF_;
        vals[i] = sc;
        mx = fmaxf(mx, sc);
    }
#pragma unroll
    for (int off = 1; off < 64; off <<= 1) mx = fmaxf(mx, __shfl_xor(mx, off));
    if (lane == 0) red[wid] = mx;
    __syncthreads();
    mx = red[0];
#pragma unroll
    for (int w = 1; w < 8; ++w) mx = fmaxf(mx, red[w]);
    __syncthreads();
    float sum = 0.f;
#pragma unroll
    for (int i = 0; i < 8; ++i) { vals[i] = __expf(vals[i] - mx); sum += vals[i]; }
#pragma unroll
    for (int off = 1; off < 64; off <<= 1) sum += __shfl_xor(sum, off);
    if (lane == 0) red[wid] = sum;
    __syncthreads();
    sum = red[0] + red[1] + red[2] + red[3] + red[4] + red[5] + red[6] + red[7];
    float inv = 1.f / sum;
#pragma unroll
    for (int i = 0; i < 8; ++i) attn[(size_t)b * S_ + i * 512 + tid] = vals[i] * inv;
}

// ---------------- context partial sums: part[c][b][e] ----------------
__global__ void ctx_partial(const float* __restrict__ attn, const float* __restrict__ enc,
                            float* __restrict__ part) {
    __shared__ float a[256];
    int c = blockIdx.x, b = blockIdx.y, t = threadIdx.x;   // 256 threads
    a[t] = attn[(size_t)b * S_ + c * 256 + t];
    __syncthreads();
    const float* ep = enc + (size_t)b * S_ * E_ + (size_t)c * 256 * E_ + t * 2;
    float x = 0.f, y = 0.f;
#pragma unroll 4
    for (int s = 0; s < 256; ++s) {
        float2 v = *(const float2*)(ep + (size_t)s * E_);
        x += a[s] * v.x;
        y += a[s] * v.y;
    }
    float* o = part + ((size_t)c * B_ + b) * E_ + t * 2;
    o[0] = x; o[1] = y;
}

__global__ void ctx_reduce(const float* __restrict__ part, float* __restrict__ ctx) {
    int idx = blockIdx.x * 256 + threadIdx.x;       // 0..32767
    float s = 0.f;
#pragma unroll
    for (int c = 0; c < 16; ++c) s += part[(size_t)c * (B_ * E_) + idx];
    ctx[idx] = s;
}

extern "C" void kernel_launch(void* const* d_in, const int* in_sizes, int n_in,
                              void* d_out, int out_size, void* d_ws, size_t ws_size,
                              hipStream_t stream) {
    const float* hidden = (const float*)d_in[0];
    const float* enc    = (const float*)d_in[1];
    const int*   mask   = (const int*)d_in[2];
    const float* Wq     = (const float*)d_in[3];
    const float* bq     = (const float*)d_in[4];
    const float* Wk     = (const float*)d_in[5];
    const float* bk     = (const float*)d_in[6];
    const float* Wv     = (const float*)d_in[7];
    const float* bv     = (const float*)d_in[8];

    float* out  = (float*)d_out;               // [B*E context][B*S attn]
    char*  ws   = (char*)d_ws;
    float*          qbuf   = (float*)ws;                                   // 131072 B
    unsigned short* wkt    = (unsigned short*)(ws + 131072);               // 524288 B
    float*          scores = (float*)(ws + 131072 + 524288);               // 1048576 B
    float*          part   = (float*)(ws + 131072 + 524288 + 1048576);     // 2097152 B

    float* ctx  = out;
    float* attn = out + B_ * E_;

    hipFuncSetAttribute((const void*)scores_kernel,
                        hipFuncAttributeMaxDynamicSharedMemorySize, 147456);

    prep_wkt<<<1024, 256, 0, stream>>>(Wk, wkt);
    prep_qb<<<64, 256, 0, stream>>>(hidden, Wq, bq, bk, qbuf);
    scores_kernel<<<dim3(32, 64), 256, 147456, stream>>>(enc, wkt, qbuf, Wv, bv, scores);
    softmax_kernel<<<64, 512, 0, stream>>>(scores, mask, attn);
    ctx_partial<<<dim3(16, 64), 256, 0, stream>>>(attn, enc, part);
    ctx_reduce<<<128, 256, 0, stream>>>(part, ctx);
}

// Round 3
// 716.328 us; speedup vs baseline: 1.1481x; 1.1481x over previous
//
#include <hip/hip_runtime.h>
#include <hip/hip_bf16.h>

#define B_ 64
#define S_ 4096
#define H_ 512
#define E_ 512
#define NEG_INF_ -1e10f

typedef __attribute__((ext_vector_type(8))) short short8;
typedef __attribute__((ext_vector_type(16))) float f32x16;

static __device__ __forceinline__ unsigned short f2bf(float f) {
    union { float f; unsigned u; } v; v.f = f;
    unsigned x = v.u;
    x += 0x7FFFu + ((x >> 16) & 1u);   // round-to-nearest-even
    return (unsigned short)(x >> 16);
}

// vendor RNE pair conversion (compiler picks the best correct lowering)
static __device__ __forceinline__ unsigned pk2(float lo, float hi) {
    float2 f; f.x = lo; f.y = hi;
    union { __hip_bfloat162 h; unsigned u; } c;
    c.h = __float22bfloat162_rn(f);
    return c.u;
}

static __device__ __forceinline__ void gload_lds16(const void* g, void* l) {
    __builtin_amdgcn_global_load_lds(
        (const __attribute__((address_space(1))) void*)g,
        (__attribute__((address_space(3))) void*)l, 16, 0, 0);
}

// ---------------- prep: Wkt[h][e] = bf16(Wk[e][h]) ----------------
__global__ void prep_wkt(const float* __restrict__ wk, unsigned short* __restrict__ wkt) {
    int idx = blockIdx.x * 256 + threadIdx.x;
    int h = idx >> 9, e = idx & 511;
    wkt[idx] = f2bf(wk[e * H_ + h]);
}

// ---------------- prep: qb[b][h] = hidden[b]@Wq[:,h] + bq[h] + bk[h] ----------------
__global__ void prep_qb(const float* __restrict__ hidden, const float* __restrict__ wq,
                        const float* __restrict__ bq, const float* __restrict__ bk,
                        float* __restrict__ qb) {
    __shared__ float hid[H_];
    int b = blockIdx.x, t = threadIdx.x;           // 256 threads
    hid[t]       = hidden[b * H_ + t];
    hid[t + 256] = hidden[b * H_ + t + 256];
    __syncthreads();
    for (int hh = t; hh < H_; hh += 256) {
        float s = 0.f;
        for (int e = 0; e < H_; ++e) s += hid[e] * wq[e * H_ + hh];
        qb[b * H_ + hh] = s + bq[hh] + bk[hh];
    }
}

// ---------------- main: partial scores over one 128-col n-chunk ----------------
// grid 8192 blocks: xcd-chunked decode -> (b, s-tile of 128, n-tile of 128)
// block 256 thr = 4 waves in 2(M)x2(N); wave tile 64x64; A(enc) in regs, B(Wkt) in LDS dbuf
__global__ __launch_bounds__(256, 2) void scores_kernel(
    const float* __restrict__ enc, const unsigned short* __restrict__ wkt,
    const float* __restrict__ qb, const float* __restrict__ wv,
    float* __restrict__ part)
{
    __shared__ char lds[65536];
    char* Bt0 = lds;
    char* Bt1 = lds + 32768;

    int id = blockIdx.x;
    int xcd = id & 7, q = id >> 3;
    int logical = xcd * 1024 + q;
    int b  = logical >> 7;
    int r7 = logical & 127;
    int st = r7 >> 2, nt = r7 & 3;
    int s0 = st * 128;

    const int tid  = threadIdx.x;
    const int lane = tid & 63;
    const int wave = tid >> 6;
    const int wr   = wave >> 1;      // M half
    const int wc   = wave & 1;       // N half
    const int l31  = lane & 31;
    const int g    = lane >> 5;

    const float* encb  = enc + ((size_t)b * S_ + s0) * E_;
    const float* aBase = encb + (size_t)(wr * 64 + l31) * E_ + g * 8;
    const int swzB = (l31 & 15) << 4;

    // ---- B staging: source-permuted global_load_lds, linear LDS dest ----
    auto stageB = [&](int T, char* buf) {
#pragma unroll
        for (int j = 0; j < 8; ++j) {
            int base_row = wave * 32 + j * 4;
            char* ldsb = buf + base_row * 256;                 // wave-uniform
            int row = base_row + (lane >> 4);
            int ks  = (lane & 15) ^ (row & 15);
            const unsigned short* gp = wkt + (size_t)(nt * 128 + row) * H_ + T * 128 + ks * 8;
            gload_lds16(gp, ldsb);
        }
    };

    float4 ar[2][4][2];
    short8 af[2][4];
    f32x16 acc[2][2];
#pragma unroll
    for (int mr = 0; mr < 2; ++mr)
#pragma unroll
        for (int nf = 0; nf < 2; ++nf)
#pragma unroll
            for (int e = 0; e < 16; ++e) acc[mr][nf][e] = 0.f;

#define LOADA(kc_) do { \
    _Pragma("unroll") for (int mr = 0; mr < 2; ++mr) \
    _Pragma("unroll") for (int ks = 0; ks < 4; ++ks) { \
        const float* ap = aBase + (size_t)mr * (32 * E_) + (kc_) * 64 + ks * 16; \
        ar[mr][ks][0] = *(const float4*)ap; \
        ar[mr][ks][1] = *(const float4*)(ap + 4); } } while (0)

    // prologue
    stageB(0, Bt0);
    stageB(1, Bt1);
    LOADA(0);
    __syncthreads();

#pragma unroll
    for (int T = 0; T < 4; ++T) {
        char* bt = (T & 1) ? Bt1 : Bt0;
#pragma unroll
        for (int kcl = 0; kcl < 2; ++kcl) {
            const int kc = T * 2 + kcl;
            // convert A(kc) f32 -> bf16 frags (RNE)
#pragma unroll
            for (int mr = 0; mr < 2; ++mr)
#pragma unroll
                for (int ks = 0; ks < 4; ++ks) {
                    union { short8 s; unsigned u[4]; } u;
                    u.u[0] = pk2(ar[mr][ks][0].x, ar[mr][ks][0].y);
                    u.u[1] = pk2(ar[mr][ks][0].z, ar[mr][ks][0].w);
                    u.u[2] = pk2(ar[mr][ks][1].x, ar[mr][ks][1].y);
                    u.u[3] = pk2(ar[mr][ks][1].z, ar[mr][ks][1].w);
                    af[mr][ks] = u.s;
                }
            if (kc < 7) { LOADA(kc + 1); }
            // MFMA: 4 ks x (2 B-frag reads + 4 mfma)
#pragma unroll
            for (int ks = 0; ks < 4; ++ks) {
                short8 bfr[2];
#pragma unroll
                for (int nf = 0; nf < 2; ++nf) {
                    int brow = wc * 64 + nf * 32 + l31;
                    int kk2  = kcl * 128 + ks * 32 + g * 16;
                    bfr[nf] = *(const short8*)(bt + brow * 256 + (kk2 ^ swzB));
                }
#pragma unroll
                for (int mr = 0; mr < 2; ++mr)
#pragma unroll
                    for (int nf = 0; nf < 2; ++nf)
                        acc[mr][nf] = __builtin_amdgcn_mfma_f32_32x32x16_bf16(
                            af[mr][ks], bfr[nf], acc[mr][nf], 0, 0, 0);
            }
        }
        __syncthreads();
        if (T < 2) stageB(T + 2, bt);
    }
#undef LOADA

    // ---- epilogue: p = sum_nf Wv[col]*tanh(qb[col]+acc) ----
    float p[2][16];
#pragma unroll
    for (int nf = 0; nf < 2; ++nf) {
        int col = nt * 128 + wc * 64 + nf * 32 + l31;
        float qv  = qb[b * H_ + col];
        float wvv = wv[col];
#pragma unroll
        for (int mr = 0; mr < 2; ++mr)
#pragma unroll
            for (int e = 0; e < 16; ++e) {
                float x  = qv + acc[mr][nf][e];
                float ex = __expf(2.f * x);
                float th = 1.f - 2.f / (ex + 1.f);
                float v  = wvv * th;
                p[mr][e] = nf ? (p[mr][e] + v) : v;
            }
    }

    // ---- reduce over 32 lanes via LDS transpose (row stride 36 floats) ----
    float* ps = (float*)lds;                     // [wave][64 rows][36]
#pragma unroll
    for (int mr = 0; mr < 2; ++mr)
#pragma unroll
        for (int e = 0; e < 16; ++e) {
            int row = mr * 32 + (e & 3) + 8 * (e >> 2) + 4 * g;
            ps[(wave * 64 + row) * 36 + l31] = p[mr][e];
        }
    __syncthreads();
    float rsum = 0.f;
    {
        const float* myrow = ps + (size_t)(wave * 64 + lane) * 36;
#pragma unroll
        for (int j = 0; j < 8; ++j) {
            float4 v = *(const float4*)(myrow + j * 4);
            rsum += (v.x + v.y) + (v.z + v.w);
        }
    }
    float* pf = (float*)(lds + 40960);           // 256 floats
    pf[wave * 64 + lane] = rsum;
    __syncthreads();
    if (tid < 128) {
        int wr2 = tid >> 6, rr = tid & 63;
        float v = pf[(wr2 * 2 + 0) * 64 + rr] + pf[(wr2 * 2 + 1) * 64 + rr];
        int s = s0 + wr2 * 64 + rr;
        part[((size_t)b * S_ + s) * 4 + nt] = v;
    }
}

// ---------------- masked softmax over S per batch row (sums 4 partials) ----------------
__global__ void softmax_kernel(const float* __restrict__ part, const int* __restrict__ mask,
                               const float* __restrict__ bvp, float* __restrict__ attn) {
    __shared__ float red[8];
    int b = blockIdx.x, tid = threadIdx.x;         // 512 threads, 8 waves
    int wid = tid >> 6, lane = tid & 63;
    float bv0 = bvp[0];
    float vals[8];
    float mx = -3.4e38f;
#pragma unroll
    for (int i = 0; i < 8; ++i) {
        int s = i * 512 + tid;
        float4 v = *(const float4*)(part + ((size_t)b * S_ + s) * 4);
        float sc = (v.x + v.y) + (v.z + v.w) + bv0;
        sc = mask[(size_t)b * S_ + s] ? sc : NEG_INF_;
        vals[i] = sc;
        mx = fmaxf(mx, sc);
    }
#pragma unroll
    for (int off = 1; off < 64; off <<= 1) mx = fmaxf(mx, __shfl_xor(mx, off));
    if (lane == 0) red[wid] = mx;
    __syncthreads();
    mx = red[0];
#pragma unroll
    for (int w = 1; w < 8; ++w) mx = fmaxf(mx, red[w]);
    __syncthreads();
    float sum = 0.f;
#pragma unroll
    for (int i = 0; i < 8; ++i) { vals[i] = __expf(vals[i] - mx); sum += vals[i]; }
#pragma unroll
    for (int off = 1; off < 64; off <<= 1) sum += __shfl_xor(sum, off);
    if (lane == 0) red[wid] = sum;
    __syncthreads();
    sum = red[0] + red[1] + red[2] + red[3] + red[4] + red[5] + red[6] + red[7];
    float inv = 1.f / sum;
#pragma unroll
    for (int i = 0; i < 8; ++i) attn[(size_t)b * S_ + i * 512 + tid] = vals[i] * inv;
}

// ---------------- context partial sums: part[c][b][e] ----------------
__global__ void ctx_partial(const float* __restrict__ attn, const float* __restrict__ enc,
                            float* __restrict__ part) {
    __shared__ float a[256];
    int c = blockIdx.x, b = blockIdx.y, t = threadIdx.x;   // 256 threads
    a[t] = attn[(size_t)b * S_ + c * 256 + t];
    __syncthreads();
    const float* ep = enc + (size_t)b * S_ * E_ + (size_t)c * 256 * E_ + t * 2;
    float x = 0.f, y = 0.f;
#pragma unroll 4
    for (int s = 0; s < 256; ++s) {
        float2 v = *(const float2*)(ep + (size_t)s * E_);
        x += a[s] * v.x;
        y += a[s] * v.y;
    }
    float* o = part + ((size_t)c * B_ + b) * E_ + t * 2;
    o[0] = x; o[1] = y;
}

__global__ void ctx_reduce(const float* __restrict__ part, float* __restrict__ ctx) {
    int idx = blockIdx.x * 256 + threadIdx.x;       // 0..32767
    float s = 0.f;
#pragma unroll
    for (int c = 0; c < 16; ++c) s += part[(size_t)c * (B_ * E_) + idx];
    ctx[idx] = s;
}

extern "C" void kernel_launch(void* const* d_in, const int* in_sizes, int n_in,
                              void* d_out, int out_size, void* d_ws, size_t ws_size,
                              hipStream_t stream) {
    const float* hidden = (const float*)d_in[0];
    const float* enc    = (const float*)d_in[1];
    const int*   mask   = (const int*)d_in[2];
    const float* Wq     = (const float*)d_in[3];
    const float* bq     = (const float*)d_in[4];
    const float* Wk     = (const float*)d_in[5];
    const float* bk     = (const float*)d_in[6];
    const float* Wv     = (const float*)d_in[7];
    const float* bv     = (const float*)d_in[8];

    float* out  = (float*)d_out;               // [B*E context][B*S attn]
    char*  ws   = (char*)d_ws;
    float*          qbuf   = (float*)ws;                         // 131072 B
    unsigned short* wkt    = (unsigned short*)(ws + 131072);     // 524288 B
    float*          pscore = (float*)(ws + 655360);              // 4 MB [b][s][4]
    float*          cpart  = (float*)(ws + 655360);              // aliases pscore (after softmax)

    float* ctx  = out;
    float* attn = out + B_ * E_;

    prep_wkt<<<1024, 256, 0, stream>>>(Wk, wkt);
    prep_qb<<<64, 256, 0, stream>>>(hidden, Wq, bq, bk, qbuf);
    scores_kernel<<<8192, 256, 0, stream>>>(enc, wkt, qbuf, Wv, pscore);
    softmax_kernel<<<64, 512, 0, stream>>>(pscore, mask, bv, attn);
    ctx_partial<<<dim3(16, 64), 256, 0, stream>>>(attn, enc, cpart);
    ctx_reduce<<<128, 256, 0, stream>>>(cpart, ctx);
}